// Round 3
// baseline (781.722 us; speedup 1.0000x reference)
//
#include <hip/hip_runtime.h>

typedef __attribute__((ext_vector_type(8))) short short8;
typedef __attribute__((ext_vector_type(4))) float f32x4;

#define AS1 __attribute__((address_space(1)))
#define AS3 __attribute__((address_space(3)))

// sizes
#define NB 16384      // batch
#define LDIM 256
#define CDIM 512
#define HDIM 1024

__device__ __forceinline__ unsigned short f2bf(float x) {
    unsigned u = __float_as_uint(x);
    u += 0x7fffu + ((u >> 16) & 1u);   // RNE; inputs are finite, no NaN guard needed
    return (unsigned short)(u >> 16);
}

__device__ __forceinline__ void gld_lds16(const unsigned short* g, unsigned short* l) {
    __builtin_amdgcn_global_load_lds((const AS1 void*)g, (AS3 void*)l, 16, 0, 0);
}

__device__ __forceinline__ float tanh_fast(float x) {
    x = fminf(fmaxf(x, -15.f), 15.f);
    float e = __expf(2.f * x);
    return (e - 1.f) * __builtin_amdgcn_rcpf(e + 1.f);   // 1-ulp rcp; output is bf16
}

// ---------------- prep: fused A1-build (blocks 0..8191) + weight transpose (8192..8841)
// A1 = bf16([pm | ctx[:, i]]) (16384 x 1024); also writes GEMM-independent outputs:
// drift position block (im*momentum), whole diffusion half, zeroed dkl slots.
// W1T (2048x1024 bf16): rows 0..1023 = Wc1^T, 1024..2047 = Wh1^T (k<512, else 0)
// W2T (512x1024 bf16): rows 0..255 = Wc2^T, 256..511 = Wh2^T; biases concatenated.
__global__ __launch_bounds__(256)
void prep(const float* __restrict__ z, const float* __restrict__ ts,
          const float* __restrict__ t, const float* __restrict__ ctx,
          const float* __restrict__ im, const float* __restrict__ dfu,
          const float* __restrict__ Wc1, const float* __restrict__ bc1,
          const float* __restrict__ Wc2, const float* __restrict__ bc2,
          const float* __restrict__ Wh1, const float* __restrict__ bh1,
          const float* __restrict__ Wh2, const float* __restrict__ bh2,
          unsigned short* __restrict__ A1, float* __restrict__ out,
          unsigned short* __restrict__ W1T, unsigned short* __restrict__ W2T,
          float* __restrict__ bias1, float* __restrict__ bias2)
{
    __shared__ float s[64][65];
    __shared__ int sh_i;
    const int tid = threadIdx.x;

    if (blockIdx.x >= 8192) {           // ---- weight transpose path ----
        const int bid = (int)blockIdx.x - 8192;
        if (bid >= 640) {               // biases
            int id = (bid - 640) * 256 + tid;
            if (id < 2048)      bias1[id] = (id < 1024) ? bc1[id] : bh1[id - 1024];
            else if (id < 2560) { int n = id - 2048; bias2[n] = (n < 256) ? bc2[n] : bh2[n - 256]; }
            return;
        }
        const int tk = bid & 15;        // k-tile (both dst have 1024 k-cols)
        const int k0 = tk * 64;
        const float* src; int srcStride, n0s, kmax, dn0;
        unsigned short* dst;
        if (bid < 512) {                // W1T, n-tiles 0..31
            const int tn = bid >> 4;
            dst = W1T; dn0 = tn * 64; srcStride = 1024;
            if (tn < 16) { src = Wc1; n0s = tn * 64;        kmax = 1024; }
            else         { src = Wh1; n0s = (tn - 16) * 64; kmax = 512;  }
        } else {                        // W2T, n-tiles 0..7
            const int tn = (bid - 512) >> 4;
            dst = W2T; dn0 = tn * 64; srcStride = 256;
            if (tn < 4) { src = Wc2; n0s = tn * 64;       kmax = 1024; }
            else        { src = Wh2; n0s = (tn - 4) * 64; kmax = 1024; }
        }
        // read: 64(k-rows) x 64(n-cols) f32 tile, coalesced float4
        #pragma unroll
        for (int rd = 0; rd < 4; ++rd) {
            int e = rd * 1024 + tid * 4;
            int r = e >> 6, c = e & 63;
            f32x4 v = {0.f, 0.f, 0.f, 0.f};
            int k = k0 + r;
            if (k < kmax) v = *(const f32x4*)(src + (size_t)k * srcStride + n0s + c);
            s[r][c + 0] = v[0]; s[r][c + 1] = v[1]; s[r][c + 2] = v[2]; s[r][c + 3] = v[3];
        }
        __syncthreads();
        // write: 64(n-rows) x 64(k-cols) bf16, coalesced short8
        #pragma unroll
        for (int wr = 0; wr < 2; ++wr) {
            int e = wr * 2048 + tid * 8;
            int on = e >> 6, ok = e & 63;
            short8 o;
            #pragma unroll
            for (int j = 0; j < 8; ++j) o[j] = (short)f2bf(s[ok + j][on]);
            *(short8*)(dst + (size_t)(dn0 + on) * 1024 + k0 + ok) = o;
        }
        return;
    }

    // ---- A1 path ----
    if (tid == 0) {
        float tv = t[0];
        int c = 0;
        #pragma unroll
        for (int q = 0; q < 16; ++q) c += (ts[q] <= tv) ? 1 : 0;   // searchsorted 'right'
        sh_i = (c < 15) ? c : 15;
    }
    __syncthreads();
    const int i = sh_i;
    size_t id = (size_t)blockIdx.x * 256 + tid;            // 2,097,152 threads
    int b  = (int)(id >> 7);
    int c0 = ((int)id & 127) << 3;
    short8 v;
    if (c0 < 512) {
        const float* zp = z + (size_t)b * 513 + c0;        // row base not 16B-aligned (513)
        float zv[8];
        #pragma unroll
        for (int q = 0; q < 8; ++q) zv[q] = zp[q];
        #pragma unroll
        for (int q = 0; q < 8; ++q) v[q] = (short)f2bf(zv[q]);
        float* drift = out + (size_t)b * 513;
        float* dif   = out + (size_t)NB * 513 + (size_t)b * 513;
        if (c0 < 256) {
            #pragma unroll
            for (int q = 0; q < 8; ++q) dif[c0 + q] = 0.f;           // diffusion position block
        } else {
            int mc = c0 - 256;
            #pragma unroll
            for (int q = 0; q < 8; ++q) {
                drift[mc + q] = im[mc + q] * zv[q];                   // position drift
                dif[c0 + q]   = dfu[mc + q];                          // diffusion momentum block
            }
        }
    } else {
        const f32x4* cp = (const f32x4*)(ctx + ((size_t)b * 16 + i) * 512 + (c0 - 512));
        f32x4 x0 = cp[0], x1 = cp[1];
        #pragma unroll
        for (int q = 0; q < 4; ++q) { v[q] = (short)f2bf(x0[q]); v[4 + q] = (short)f2bf(x1[q]); }
    }
    *(short8*)(A1 + id * 8) = v;
    if (id < NB) {
        out[id * 513 + 512] = 0.f;                          // drift dkl slot (atomic target)
        out[(size_t)NB * 513 + id * 513 + 512] = 0.f;       // diffusion dkl slot
    }
}

// ---------------- layer-1 bf16 MFMA GEMM, m97 structure, BK=64, XCD-swizzled ---------
// 128x128 tile, BK=64 (half the barrier drains vs BK=32), 4 waves of 64x64, 16x16x32.
// C = tanh(A1 @ W1 + bias1) -> H bf16 (ldc 2048); ntile>=8 (prior half) uses K=512
__global__ __launch_bounds__(256)
void gemm1(const unsigned short* __restrict__ A, const unsigned short* __restrict__ BT,
           const float* __restrict__ bias, unsigned short* __restrict__ Hout)
{
    __shared__ unsigned short sA[128 * 64];
    __shared__ unsigned short sB[128 * 64];

    const int tid  = threadIdx.x;
    const int lane = tid & 63;
    const int wave = tid >> 6;

    // XCD swizzle: 2048 wgs -> 256-wg contiguous chunk per XCD (16 consecutive m-tiles).
    int lin = blockIdx.y * 16 + blockIdx.x;
    lin = (lin & 7) * 256 + (lin >> 3);         // bijective (2048 % 8 == 0)
    const int ntile = lin & 15;
    const int mtile = lin >> 4;
    const int kdim  = (ntile < 8) ? 1024 : 512;

    const int m0 = mtile * 128;
    const int n0 = ntile * 128;

    // staging: 4 rounds x 256 threads x 16B per 128x64 tile (16 KB each)
    // round r, thread tid -> chunk r*256+tid: row = r*32 + tid>>3, kcol = (tid&7)*8
    const int srow = tid >> 3;
    const int sc   = (tid & 7) * 8;
    const unsigned short* aG = A  + (size_t)(m0 + srow) * 1024 + sc;
    const unsigned short* bG = BT + (size_t)(n0 + srow) * 1024 + sc;
    unsigned short* const sAb = sA + wave * 512;   // + r*2048; HW adds lane*16B
    unsigned short* const sBb = sB + wave * 512;

    const int wm = (wave & 1) * 64;
    const int wn = (wave >> 1) * 64;
    const int lr = lane & 15;
    const int kq = (lane >> 4) * 8;

    f32x4 acc[4][4] = {};

    for (int k0 = 0; k0 < kdim; k0 += 64) {
        #pragma unroll
        for (int r = 0; r < 4; ++r) {
            gld_lds16(aG + (size_t)r * 32 * 1024 + k0, sAb + r * 2048);
            gld_lds16(bG + (size_t)r * 32 * 1024 + k0, sBb + r * 2048);
        }
        __syncthreads();

        #pragma unroll
        for (int kk = 0; kk < 64; kk += 32) {
            short8 af[4], bfr[4];
            #pragma unroll
            for (int i = 0; i < 4; ++i)
                af[i] = *(const short8*)&sA[(wm + i * 16 + lr) * 64 + kk + kq];
            #pragma unroll
            for (int i = 0; i < 4; ++i)
                bfr[i] = *(const short8*)&sB[(wn + i * 16 + lr) * 64 + kk + kq];

            #pragma unroll
            for (int i = 0; i < 4; ++i)
                #pragma unroll
                for (int j = 0; j < 4; ++j)
                    acc[i][j] = __builtin_amdgcn_mfma_f32_16x16x32_bf16(af[i], bfr[j], acc[i][j], 0, 0, 0);
        }
        __syncthreads();
    }

    // epilogue: C/D layout col=lane&15, row=(lane>>4)*4+reg
    const int rquad = (lane >> 4) * 4;
    #pragma unroll
    for (int i = 0; i < 4; ++i) {
        const int gr = m0 + wm + i * 16 + rquad;
        #pragma unroll
        for (int j = 0; j < 4; ++j) {
            const int gc = n0 + wn + j * 16 + lr;
            const float bs = bias[gc];
            #pragma unroll
            for (int r = 0; r < 4; ++r) {
                float x = acc[i][j][r] + bs;
                Hout[(size_t)(gr + r) * 2048 + gc] = f2bf(tanh_fast(x));
            }
        }
    }
}

// ---------------- layer-2 GEMM fused with posterior write + dkl ----------------------
// BK=64; A (H tiles) staged in LDS (8x intra-block reuse); B (W2T, 1 MB, L2-resident)
// read DIRECTLY into fragments (zero intra-block reuse -> staging bought nothing).
// 512 threads (8 waves), 64 rows x 128 cols of BOTH halves; wave owns a 16-col slice.
__global__ __launch_bounds__(512)
void gemm2_fused(const unsigned short* __restrict__ Hm, const unsigned short* __restrict__ W2T,
                 const float* __restrict__ bias2, const float* __restrict__ dfu,
                 float* __restrict__ out)
{
    __shared__ unsigned short sAp[64 * 64];    // posterior A tile (H cols k0..k0+63)
    __shared__ unsigned short sAq[64 * 64];    // prior    A tile (H cols 1024+k0..)

    const int tid  = threadIdx.x;
    const int lane = tid & 63;
    const int w    = tid >> 6;                 // 0..7

    // XCD swizzle: 512 wgs -> 64 contiguous per XCD (matches gemm1's H stripe placement)
    int lin = blockIdx.y * 2 + blockIdx.x;
    lin = (lin & 7) * 64 + (lin >> 3);          // bijective (512 % 8 == 0)
    const int n0 = (lin & 1) * 128;
    const int m0 = (lin >> 1) * 64;

    // A staging: 512 chunks of 16B per tile = 1 round: row = tid>>3, kcol = (tid&7)*8
    const int srow = tid >> 3;
    const int sc   = (tid & 7) * 8;
    const unsigned short* aGp = Hm + (size_t)(m0 + srow) * 2048 + sc;
    const unsigned short* aGq = aGp + 1024;
    unsigned short* const aLp = sAp + w * 512;
    unsigned short* const aLq = sAq + w * 512;

    const int wn = w * 16;                      // wave's 16-col slice
    const int lr = lane & 15;
    const int kq = (lane >> 4) * 8;

    // direct B fragment pointers (per-lane row, 16B-aligned)
    const unsigned short* bPr = W2T + (size_t)(n0 + wn + lr) * 1024 + kq;
    const unsigned short* bQr = bPr + 256 * 1024;

    f32x4 accp[4] = {};
    f32x4 accq[4] = {};

    for (int k0 = 0; k0 < 1024; k0 += 64) {
        // issue B loads early: latency hides under staging + barrier + LDS reads
        short8 bp0 = *(const short8*)(bPr + k0);
        short8 bp1 = *(const short8*)(bPr + k0 + 32);
        short8 bq0 = *(const short8*)(bQr + k0);
        short8 bq1 = *(const short8*)(bQr + k0 + 32);

        gld_lds16(aGp + k0, aLp);
        gld_lds16(aGq + k0, aLq);
        __syncthreads();

        short8 afp[4], afq[4];
        #pragma unroll
        for (int i = 0; i < 4; ++i) {
            afp[i] = *(const short8*)&sAp[(i * 16 + lr) * 64 + kq];
            afq[i] = *(const short8*)&sAq[(i * 16 + lr) * 64 + kq];
        }
        #pragma unroll
        for (int i = 0; i < 4; ++i) {
            accp[i] = __builtin_amdgcn_mfma_f32_16x16x32_bf16(afp[i], bp0, accp[i], 0, 0, 0);
            accq[i] = __builtin_amdgcn_mfma_f32_16x16x32_bf16(afq[i], bq0, accq[i], 0, 0, 0);
        }
        #pragma unroll
        for (int i = 0; i < 4; ++i) {
            afp[i] = *(const short8*)&sAp[(i * 16 + lr) * 64 + 32 + kq];
            afq[i] = *(const short8*)&sAq[(i * 16 + lr) * 64 + 32 + kq];
        }
        #pragma unroll
        for (int i = 0; i < 4; ++i) {
            accp[i] = __builtin_amdgcn_mfma_f32_16x16x32_bf16(afp[i], bp1, accp[i], 0, 0, 0);
            accq[i] = __builtin_amdgcn_mfma_f32_16x16x32_bf16(afq[i], bq1, accq[i], 0, 0, 0);
        }
        __syncthreads();
    }

    // epilogue
    const int gc = n0 + wn + lr;
    const float bcv = bias2[gc];
    const float bhv = bias2[256 + gc];
    float d   = dfu[gc];
    float sgn = (d > 0.f) ? 1.f : ((d < 0.f) ? -1.f : 0.f);
    float sd  = (fabsf(d) > 1e-7f) ? d : sgn * 1e-7f;
    const int rquad = (lane >> 4) * 4;

    #pragma unroll
    for (int i = 0; i < 4; ++i) {
        #pragma unroll
        for (int r = 0; r < 4; ++r) {
            const int gr = m0 + i * 16 + rquad + r;
            float post = accp[i][r] + bcv;
            float pri  = accq[i][r] + bhv;
            out[(size_t)gr * 513 + 256 + gc] = post;
            float qq = (pri - post) / sd;
            float s2 = qq * qq;
            #pragma unroll
            for (int m = 1; m < 16; m <<= 1) s2 += __shfl_xor(s2, m, 64);
            if (lr == 0) atomicAdd(&out[(size_t)gr * 513 + 512], s2);
        }
    }
}

extern "C" void kernel_launch(void* const* d_in, const int* in_sizes, int n_in,
                              void* d_out, int out_size, void* d_ws, size_t ws_size,
                              hipStream_t stream) {
    const float* z    = (const float*)d_in[0];
    const float* ts   = (const float*)d_in[1];
    const float* t    = (const float*)d_in[2];
    const float* ctx  = (const float*)d_in[3];
    const float* im   = (const float*)d_in[4];
    const float* dfu  = (const float*)d_in[5];
    const float* Wc1  = (const float*)d_in[6];
    const float* bc1  = (const float*)d_in[7];
    const float* Wc2  = (const float*)d_in[8];
    const float* bc2  = (const float*)d_in[9];
    const float* Wh1  = (const float*)d_in[10];
    const float* bh1  = (const float*)d_in[11];
    const float* Wh2  = (const float*)d_in[12];
    const float* bh2  = (const float*)d_in[13];

    char* ws = (char*)d_ws;
    unsigned short* A1  = (unsigned short*)(ws);                       // 33,554,432 B
    unsigned short* H   = (unsigned short*)(ws + 33554432ull);         // 67,108,864 B
    unsigned short* W1T = (unsigned short*)(ws + 100663296ull);        //  4,194,304 B
    unsigned short* W2T = (unsigned short*)(ws + 104857600ull);        //  1,048,576 B
    float*          b1  = (float*)(ws + 105906176ull);                 //      8,192 B
    float*          b2  = (float*)(ws + 105914368ull);                 //      2,048 B

    float* out = (float*)d_out;

    // blocks 0..8191: A1 build; 8192..8841: weight transpose + biases
    prep<<<8842, 256, 0, stream>>>(z, ts, t, ctx, im, dfu,
                                   Wc1, bc1, Wc2, bc2, Wh1, bh1, Wh2, bh2,
                                   A1, out, W1T, W2T, b1, b2);

    dim3 g1(16, 128);
    gemm1<<<g1, 256, 0, stream>>>(A1, W1T, b1, H);

    dim3 g2(2, 256);
    gemm2_fused<<<g2, 512, 0, stream>>>(H, W2T, b2, dfu, out);
}